// Round 1
// baseline (1546.774 us; speedup 1.0000x reference)
//
#include <hip/hip_runtime.h>

#define EPSV 1e-15f
#define PEPS 1e-5f

// ---------------- Kernel A: Ux[b,t,:] = mob_mat_mul(u, x[b,t,:]) -> out ----------------
// 32 rows per block, 256 threads. x tile staged transposed in LDS, u streamed from L2.
__global__ __launch_bounds__(256) void ux_kernel(
    const float* __restrict__ x, const float* __restrict__ u,
    float* __restrict__ out)
{
  __shared__ __align__(16) float xsT[256][36];  // [i][r], pad 36 keeps 16B align + breaks banks
  __shared__ float rowscale[32];
  __shared__ float xnorm[32];
  __shared__ float fscale[32];

  const int tid = threadIdx.x;
  const int wave = tid >> 6, lane = tid & 63;
  const int base = blockIdx.x * 32;

  // load 32 rows (coalesced), store transposed
  #pragma unroll
  for (int k = 0; k < 32; ++k)
    xsT[tid][k] = x[(base + k) * 256 + tid];
  __syncthreads();

  // per-row Σx, Σx² -> projection scale + x_norm (= ||proj(x)+EPS||)
  #pragma unroll
  for (int rr = 0; rr < 8; ++rr) {
    const int r = wave * 8 + rr;
    float s1 = 0.f, s2 = 0.f;
    #pragma unroll
    for (int c = 0; c < 4; ++c) {
      float v = xsT[lane + 64 * c][r];
      s1 += v; s2 += v * v;
    }
    #pragma unroll
    for (int off = 32; off; off >>= 1) {
      s1 += __shfl_xor(s1, off);
      s2 += __shfl_xor(s2, off);
    }
    if (lane == 0) {
      float sc = (1.f - PEPS) / fmaxf(s2, 1.f - PEPS);
      rowscale[r] = sc;
      xnorm[r] = sqrtf(sc * sc * s2 + 2.f * sc * EPSV * s1 + 256.f * EPSV * EPSV);
    }
  }
  __syncthreads();

  // GEMM: thread j accumulates 32 rows; projection scale folded in afterwards (linear)
  float acc[32];
  #pragma unroll
  for (int r = 0; r < 32; ++r) acc[r] = 0.f;
  for (int i = 0; i < 256; ++i) {
    float uij = u[i * 256 + tid];
    const float4* xr = reinterpret_cast<const float4*>(&xsT[i][0]);
    #pragma unroll
    for (int r4 = 0; r4 < 8; ++r4) {
      float4 xv = xr[r4];
      acc[r4 * 4 + 0] += xv.x * uij;
      acc[r4 * 4 + 1] += xv.y * uij;
      acc[r4 * 4 + 2] += xv.z * uij;
      acc[r4 * 4 + 3] += xv.w * uij;
    }
  }
  __syncthreads();  // done reading xsT, reuse as Ms[32][256]
  float* Ms = &xsT[0][0];
  #pragma unroll
  for (int r = 0; r < 32; ++r)
    Ms[r * 256 + tid] = acc[r] * rowscale[r];  // Mx = proj(x) @ u
  __syncthreads();

  // per-row ΣMx, ΣMx² -> tanh scaling + final projection, folded into one scale
  #pragma unroll
  for (int rr = 0; rr < 8; ++rr) {
    const int r = wave * 8 + rr;
    float s1 = 0.f, s2 = 0.f;
    #pragma unroll
    for (int c = 0; c < 4; ++c) {
      float v = Ms[r * 256 + lane + 64 * c];
      s1 += v; s2 += v * v;
    }
    #pragma unroll
    for (int off = 32; off; off >>= 1) {
      s1 += __shfl_xor(s1, off);
      s2 += __shfl_xor(s2, off);
    }
    if (lane == 0) {
      float mxn = sqrtf(s2 + 2.f * EPSV * s1 + 256.f * EPSV * EPSV);  // ||Mx+EPS||
      float xn = xnorm[r];
      float at = 0.5f * logf((1.f + xn) / (1.f - xn));                // atanh(x_norm)
      float g = tanhf(mxn / xn * at) / mxn;
      float pn2 = g * g * s2;                                        // ||g·Mx||²
      fscale[r] = g * ((1.f - PEPS) / fmaxf(pn2, 1.f - PEPS));
    }
  }
  __syncthreads();
  #pragma unroll
  for (int r = 0; r < 32; ++r)
    out[(base + r) * 256 + tid] = fscale[r] * Ms[r * 256 + tid];
}

// ---------------- Kernel B: sequential recurrence, one block per batch row ----------------
// 1024 threads: thread (j = tid&255, k4 = tid>>8) holds w[64*k4 .. 64*k4+63][j] in 64 VGPRs.
// Per step: matvec (4-way K-split) + 7 fused dot-reductions; all norms/mob_add scales
// derived analytically in scalars. out[] holds Ux on entry, h_new on exit (same address).
__global__ __launch_bounds__(1024) void rnn_kernel(
    const float* __restrict__ w, const float* __restrict__ bvec,
    float* __restrict__ out, int S)
{
  __shared__ __align__(16) float hp[256];      // projected h for the matvec
  __shared__ float partial[4][256];
  __shared__ float red[4][8];

  const int tid = threadIdx.x;
  const int j = tid & 255, k4 = tid >> 8;
  const int wave = tid >> 6, lane = tid & 63;

  float wreg[64];
  #pragma unroll
  for (int ii = 0; ii < 64; ++ii)
    wreg[ii] = w[(k4 * 64 + ii) * 256 + j];    // coalesced across lanes

  const float vb = bvec[j] + EPSV;             // v of second mob_add (constant)

  // precompute Σvb, Σvb² once
  {
    float q0 = vb, q1 = vb * vb;
    #pragma unroll
    for (int off = 32; off; off >>= 1) {
      q0 += __shfl_xor(q0, off);
      q1 += __shfl_xor(q1, off);
    }
    if (tid < 256 && lane == 0) { red[wave][0] = q0; red[wave][1] = q1; }
  }
  if (tid < 256) hp[j] = 0.f;                  // h0 = 0 (projected = 0)
  __syncthreads();
  const float S_vb  = red[0][0] + red[1][0] + red[2][0] + red[3][0];
  const float S_vb2 = red[0][1] + red[1][1] + red[2][1] + red[3][1];
  __syncthreads();

  const int rowbase = blockIdx.x * S * 256;
  float S_h = 0.f, S_h2 = 0.f;                 // analytic Σh, Σh² of current h

  for (int t = 0; t < S; ++t) {
    // prefetch Ux early (hides HBM latency under the matvec)
    float ux = 0.f;
    if (tid < 256) ux = out[rowbase + t * 256 + j];

    // matvec partial: Σ_i hp[i]·w[i][j] over this thread's 64-wide K slice
    float a0 = 0.f, a1 = 0.f, a2 = 0.f, a3 = 0.f;
    const float4* hrow = reinterpret_cast<const float4*>(&hp[k4 * 64]);
    #pragma unroll
    for (int ii = 0; ii < 16; ++ii) {
      float4 h4 = hrow[ii];                    // LDS broadcast (all lanes same addr)
      a0 += wreg[ii * 4 + 0] * h4.x;
      a1 += wreg[ii * 4 + 1] * h4.y;
      a2 += wreg[ii * 4 + 2] * h4.z;
      a3 += wreg[ii * 4 + 3] * h4.w;
    }
    partial[k4][j] = (a0 + a1) + (a2 + a3);
    __syncthreads();

    float m = 0.f, v = 0.f;
    if (tid < 256) {
      m = (partial[0][j] + partial[1][j]) + (partial[2][j] + partial[3][j]); // Mx[j]
      v = ux + EPSV;
      float p0 = m, p1 = m * m, p2 = m * v, p3 = v, p4 = v * v, p5 = m * vb, p6 = v * vb;
      #pragma unroll
      for (int off = 32; off; off >>= 1) {
        p0 += __shfl_xor(p0, off); p1 += __shfl_xor(p1, off);
        p2 += __shfl_xor(p2, off); p3 += __shfl_xor(p3, off);
        p4 += __shfl_xor(p4, off); p5 += __shfl_xor(p5, off);
        p6 += __shfl_xor(p6, off);
      }
      if (lane == 0) {
        red[wave][0] = p0; red[wave][1] = p1; red[wave][2] = p2; red[wave][3] = p3;
        red[wave][4] = p4; red[wave][5] = p5; red[wave][6] = p6;
      }
    }
    __syncthreads();

    if (tid < 256) {
      const float S_Mx  = red[0][0] + red[1][0] + red[2][0] + red[3][0];
      const float S_Mx2 = red[0][1] + red[1][1] + red[2][1] + red[3][1];
      const float S_Mxv = red[0][2] + red[1][2] + red[2][2] + red[3][2];
      const float S_v   = red[0][3] + red[1][3] + red[2][3] + red[3][3];
      const float S_v2  = red[0][4] + red[1][4] + red[2][4] + red[3][4];
      const float S_Mxb = red[0][5] + red[1][5] + red[2][5] + red[3][5];
      const float S_vvb = red[0][6] + red[1][6] + red[2][6] + red[3][6];

      // mob_mat_mul(w, h) scalars: x_norm of proj(h), Mx_norm, tanh scale, projection
      float s_hp = (1.f - PEPS) / fmaxf(S_h2, 1.f - PEPS);
      float xn = sqrtf(s_hp * s_hp * S_h2 + 2.f * s_hp * EPSV * S_h + 256.f * EPSV * EPSV);
      float mxn = sqrtf(S_Mx2 + 2.f * EPSV * S_Mx + 256.f * EPSV * EPSV);
      float at = 0.5f * logf((1.f + xn) / (1.f - xn));
      float g = tanhf(mxn / xn * at) / mxn;          // Wh_pre = g·Mx
      float sw = (1.f - PEPS) / fmaxf(g * g * S_Mx2, 1.f - PEPS);
      float beta = g * sw;                           // Wh = beta·Mx (projected)

      // mob_add(Wh, v),  v = Ux + EPS
      float nuv = 2.f * beta * S_Mxv;
      float nu  = beta * beta * S_Mx2;
      float nv  = S_v2;
      float den = 1.f + nuv + nv * nu;
      float cA = (1.f + nuv + nv) / den;
      float cB = (1.f - nu) / den;
      float cAb = cA * beta;                         // r1 = cAb·Mx + cB·v
      float S_r1  = cAb * S_Mx + cB * S_v;
      float S_r12 = cAb * cAb * S_Mx2 + 2.f * cAb * cB * S_Mxv + cB * cB * S_v2;
      float S_r1b = cAb * S_Mxb + cB * S_vvb;
      float s1 = (1.f - PEPS) / fmaxf(S_r12, 1.f - PEPS);   // project
      float S_U = s1 * S_r1, S_U2 = s1 * s1 * S_r12, S_Ub = s1 * S_r1b;

      // mob_add(U, b),  vb = b + EPS
      float nuv2 = 2.f * S_Ub;
      float den2 = 1.f + nuv2 + S_vb2 * S_U2;
      float dA = (1.f + nuv2 + S_vb2) / den2;
      float dB = (1.f - S_U2) / den2;                // h_pre = dA·U + dB·vb
      float S_hn  = dA * S_U + dB * S_vb;
      float S_hn2 = dA * dA * S_U2 + 2.f * dA * dB * S_Ub + dB * dB * S_vb2;
      float s2 = (1.f - PEPS) / fmaxf(S_hn2, 1.f - PEPS);   // project

      float km = s2 * dA * s1 * cAb;
      float kv = s2 * dA * s1 * cB;
      float kb = s2 * dB;
      float hnew = km * m + kv * v + kb * vb;
      out[rowbase + t * 256 + j] = hnew;

      S_h  = s2 * S_hn;
      S_h2 = s2 * s2 * S_hn2;
      float snext = (1.f - PEPS) / fmaxf(S_h2, 1.f - PEPS); // next step's projection
      hp[j] = snext * hnew;
    }
    __syncthreads();
  }
}

extern "C" void kernel_launch(void* const* d_in, const int* in_sizes, int n_in,
                              void* d_out, int out_size, void* d_ws, size_t ws_size,
                              hipStream_t stream) {
  const float* x = (const float*)d_in[0];   // [B,S,I]
  const float* w = (const float*)d_in[1];   // [H,H]
  const float* u = (const float*)d_in[2];   // [I,H]
  const float* b = (const float*)d_in[3];   // [H]
  float* out = (float*)d_out;               // [B,S,H]

  const int nrows = in_sizes[0] / 256;      // B*S
  const int S = 512;
  const int B = nrows / S;

  ux_kernel<<<nrows / 32, 256, 0, stream>>>(x, u, out);
  rnn_kernel<<<B, 1024, 0, stream>>>(w, b, out, S);
}

// Round 2
// 961.291 us; speedup vs baseline: 1.6091x; 1.6091x over previous
//
#include <hip/hip_runtime.h>

#define EPSV 1e-15f
#define PEPS 1e-5f

__device__ __forceinline__ float frcp(float x) { return __builtin_amdgcn_rcpf(x); }
__device__ __forceinline__ float fexp2(float x) { return __builtin_amdgcn_exp2f(x); }
__device__ __forceinline__ float flog2(float x) { return __builtin_amdgcn_logf(x); }
// projection scale: exactly 1.0 when norm² <= 1-PEPS (matches reference), else (1-PEPS)/n2
__device__ __forceinline__ float projscale(float n2) {
  return n2 > (1.f - PEPS) ? (1.f - PEPS) * frcp(n2) : 1.f;
}

// ---------------- Kernel A: Ux[b,t,:] = mob_mat_mul(u, x[b,t,:]) -> out ----------------
// 256 threads, 32 rows/block. Thread (lane, wv): cols 4*lane..+3, rows 8*wv..+7.
// Per i: 1 coalesced b128 u-load + 2 broadcast b128 x-reads + 32 FMAs.
__global__ __launch_bounds__(256) void ux_kernel(
    const float* __restrict__ x, const float* __restrict__ u,
    float* __restrict__ out)
{
  __shared__ __align__(16) float xsT[256][36];   // [i][row], 36-pad keeps 16B align

  const int tid = threadIdx.x;
  const int lane = tid & 63, wv = tid >> 6;
  const long long base = (long long)blockIdx.x * 32;

  // load 32 rows (coalesced), store transposed via b128 writes
  #pragma unroll
  for (int k4 = 0; k4 < 8; ++k4) {
    float t0 = x[(base + k4 * 4 + 0) * 256 + tid];
    float t1 = x[(base + k4 * 4 + 1) * 256 + tid];
    float t2 = x[(base + k4 * 4 + 2) * 256 + tid];
    float t3 = x[(base + k4 * 4 + 3) * 256 + tid];
    float4 v; v.x = t0; v.y = t1; v.z = t2; v.w = t3;
    *reinterpret_cast<float4*>(&xsT[tid][k4 * 4]) = v;
  }
  __syncthreads();

  // phase 1: Σx, Σx² for this wave's 8 rows (conflict-free b128 reads + butterfly)
  float s1[8], s2[8];
  #pragma unroll
  for (int r = 0; r < 8; ++r) { s1[r] = 0.f; s2[r] = 0.f; }
  #pragma unroll
  for (int c = 0; c < 4; ++c) {
    const int i = lane + 64 * c;
    float4 xa = *reinterpret_cast<const float4*>(&xsT[i][8 * wv]);
    float4 xb = *reinterpret_cast<const float4*>(&xsT[i][8 * wv + 4]);
    s1[0] += xa.x; s2[0] += xa.x * xa.x;
    s1[1] += xa.y; s2[1] += xa.y * xa.y;
    s1[2] += xa.z; s2[2] += xa.z * xa.z;
    s1[3] += xa.w; s2[3] += xa.w * xa.w;
    s1[4] += xb.x; s2[4] += xb.x * xb.x;
    s1[5] += xb.y; s2[5] += xb.y * xb.y;
    s1[6] += xb.z; s2[6] += xb.z * xb.z;
    s1[7] += xb.w; s2[7] += xb.w * xb.w;
  }
  #pragma unroll
  for (int off = 32; off; off >>= 1) {
    #pragma unroll
    for (int r = 0; r < 8; ++r) {
      s1[r] += __shfl_xor(s1[r], off);
      s2[r] += __shfl_xor(s2[r], off);
    }
  }
  float rs[8], xnr[8];
  #pragma unroll
  for (int r = 0; r < 8; ++r) {
    float sc = projscale(s2[r]);
    rs[r] = sc;
    xnr[r] = sqrtf(sc * sc * s2[r] + 2.f * sc * EPSV * s1[r] + 256.f * EPSV * EPSV);
  }

  // GEMM: acc[r].q = Σ_i x[row][i] * u[i][4*lane+q]
  float4 acc[8];
  #pragma unroll
  for (int r = 0; r < 8; ++r) { acc[r].x = 0.f; acc[r].y = 0.f; acc[r].z = 0.f; acc[r].w = 0.f; }
  #pragma unroll 2
  for (int i = 0; i < 256; ++i) {
    float4 uv = *reinterpret_cast<const float4*>(&u[i * 256 + 4 * lane]);
    float4 xa = *reinterpret_cast<const float4*>(&xsT[i][8 * wv]);
    float4 xb = *reinterpret_cast<const float4*>(&xsT[i][8 * wv + 4]);
    acc[0].x += uv.x * xa.x; acc[0].y += uv.y * xa.x; acc[0].z += uv.z * xa.x; acc[0].w += uv.w * xa.x;
    acc[1].x += uv.x * xa.y; acc[1].y += uv.y * xa.y; acc[1].z += uv.z * xa.y; acc[1].w += uv.w * xa.y;
    acc[2].x += uv.x * xa.z; acc[2].y += uv.y * xa.z; acc[2].z += uv.z * xa.z; acc[2].w += uv.w * xa.z;
    acc[3].x += uv.x * xa.w; acc[3].y += uv.y * xa.w; acc[3].z += uv.z * xa.w; acc[3].w += uv.w * xa.w;
    acc[4].x += uv.x * xb.x; acc[4].y += uv.y * xb.x; acc[4].z += uv.z * xb.x; acc[4].w += uv.w * xb.x;
    acc[5].x += uv.x * xb.y; acc[5].y += uv.y * xb.y; acc[5].z += uv.z * xb.y; acc[5].w += uv.w * xb.y;
    acc[6].x += uv.x * xb.z; acc[6].y += uv.y * xb.z; acc[6].z += uv.z * xb.z; acc[6].w += uv.w * xb.z;
    acc[7].x += uv.x * xb.w; acc[7].y += uv.y * xb.w; acc[7].z += uv.z * xb.w; acc[7].w += uv.w * xb.w;
  }

  // phase 2: per-row ΣMx, ΣMx² from accumulators (butterfly), scalar chain, store
  float t1s[8], t2s[8];
  #pragma unroll
  for (int r = 0; r < 8; ++r) {
    t1s[r] = acc[r].x + acc[r].y + acc[r].z + acc[r].w;
    t2s[r] = acc[r].x * acc[r].x + acc[r].y * acc[r].y + acc[r].z * acc[r].z + acc[r].w * acc[r].w;
  }
  #pragma unroll
  for (int off = 32; off; off >>= 1) {
    #pragma unroll
    for (int r = 0; r < 8; ++r) {
      t1s[r] += __shfl_xor(t1s[r], off);
      t2s[r] += __shfl_xor(t2s[r], off);
    }
  }
  #pragma unroll
  for (int r = 0; r < 8; ++r) {
    float Sm  = rs[r] * t1s[r];
    float Sm2 = rs[r] * rs[r] * t2s[r];
    float mxn = sqrtf(Sm2 + 2.f * EPSV * Sm + 256.f * EPSV * EPSV);
    float xn = xnr[r];
    float at = 0.34657359f * flog2((1.f + xn) * frcp(1.f - xn));   // 0.5*ln((1+x)/(1-x))
    float arg = mxn * frcp(xn) * at;
    float e2 = fexp2(arg * 2.8853902f);                            // e^{2*arg}
    float th = 1.f - 2.f * frcp(e2 + 1.f);
    float g = th * frcp(mxn);
    float fs = g * projscale(g * g * Sm2) * rs[r];
    float4 o;
    o.x = fs * acc[r].x; o.y = fs * acc[r].y; o.z = fs * acc[r].z; o.w = fs * acc[r].w;
    reinterpret_cast<float4*>(out)[(base + 8 * wv + r) * 64 + lane] = o;
  }
}

// ---------------- Kernel B: sequential recurrence, one block per batch row ----------------
// 512 threads: thread (wv = tid>>6 -> K-slice of 32, lane -> cols 4*lane..+3) holds w in
// 128 VGPRs. Wave 0 alone does the dots/scalar chain/write (its 64 lanes cover all 256 cols).
__global__ __launch_bounds__(512, 2) void rnn_kernel(
    const float* __restrict__ w, const float* __restrict__ bvec,
    float* __restrict__ out, int S)
{
  __shared__ __align__(16) float h_lds[256];
  __shared__ __align__(16) float partial[8][256];
  __shared__ __align__(16) float v_lds[2][256];

  const int tid = threadIdx.x;
  const int lane = tid & 63;
  const int wv = tid >> 6;                       // 0..7

  // weights: wreg[ii].q = w[(32*wv+ii)][4*lane+q]
  float4 wreg[32];
  #pragma unroll
  for (int ii = 0; ii < 32; ++ii)
    wreg[ii] = *reinterpret_cast<const float4*>(&w[(wv * 32 + ii) * 256 + 4 * lane]);

  float4 vb4 = *reinterpret_cast<const float4*>(&bvec[4 * lane]);
  vb4.x += EPSV; vb4.y += EPSV; vb4.z += EPSV; vb4.w += EPSV;

  // Σvb, Σvb² (each wave's 64 lanes cover all 256 cols)
  float S_vb  = vb4.x + vb4.y + vb4.z + vb4.w;
  float S_vb2 = vb4.x * vb4.x + vb4.y * vb4.y + vb4.z * vb4.z + vb4.w * vb4.w;
  #pragma unroll
  for (int off = 32; off; off >>= 1) {
    S_vb  += __shfl_xor(S_vb, off);
    S_vb2 += __shfl_xor(S_vb2, off);
  }

  const long long rb4 = (long long)blockIdx.x * S * 64;   // float4 index base
  const float4* outv = reinterpret_cast<const float4*>(out);
  float4* outw = reinterpret_cast<float4*>(out);

  float4 vnext;
  if (wv == 0) {
    reinterpret_cast<float4*>(h_lds)[lane] = float4{0.f, 0.f, 0.f, 0.f};
    reinterpret_cast<float4*>(v_lds[0])[lane] = outv[rb4 + lane];       // v for t=0
    vnext = outv[rb4 + 64 + lane];                                      // v for t=1
  }
  __syncthreads();

  float S_h = 0.f, S_h2 = 0.f;

  for (int t = 0; t < S; ++t) {
    // ---- matvec: a.q = Σ_{ii} w[32wv+ii][4lane+q] * h[32wv+ii] ----
    float4 a = {0.f, 0.f, 0.f, 0.f};
    const float4* hp = reinterpret_cast<const float4*>(&h_lds[wv * 32]);
    #pragma unroll
    for (int i4 = 0; i4 < 8; ++i4) {
      float4 h4 = hp[i4];                        // wave-uniform broadcast
      float4 w0 = wreg[i4 * 4 + 0], w1 = wreg[i4 * 4 + 1];
      float4 w2 = wreg[i4 * 4 + 2], w3 = wreg[i4 * 4 + 3];
      a.x += w0.x * h4.x; a.y += w0.y * h4.x; a.z += w0.z * h4.x; a.w += w0.w * h4.x;
      a.x += w1.x * h4.y; a.y += w1.y * h4.y; a.z += w1.z * h4.y; a.w += w1.w * h4.y;
      a.x += w2.x * h4.z; a.y += w2.y * h4.z; a.z += w2.z * h4.z; a.w += w2.w * h4.z;
      a.x += w3.x * h4.w; a.y += w3.y * h4.w; a.z += w3.z * h4.w; a.w += w3.w * h4.w;
    }
    *reinterpret_cast<float4*>(&partial[wv][4 * lane]) = a;

    // v prefetch pipeline (wave 0): stage v[t+1] (loaded last step), issue load v[t+2]
    if (wv == 0) {
      if (t + 1 < S) reinterpret_cast<float4*>(v_lds[(t + 1) & 1])[lane] = vnext;
      if (t + 2 < S) vnext = outv[rb4 + (t + 2) * 64 + lane];
    }
    __syncthreads();                             // partials + v_lds[t&1] ready

    if (wv == 0) {
      // ---- combine K-partials + 7 dots over 256 cols (4/lane) ----
      float4 m4 = {0.f, 0.f, 0.f, 0.f};
      #pragma unroll
      for (int k = 0; k < 8; ++k) {
        float4 p = *reinterpret_cast<const float4*>(&partial[k][4 * lane]);
        m4.x += p.x; m4.y += p.y; m4.z += p.z; m4.w += p.w;
      }
      float4 v4 = reinterpret_cast<const float4*>(v_lds[t & 1])[lane];
      v4.x += EPSV; v4.y += EPSV; v4.z += EPSV; v4.w += EPSV;

      float p0 = m4.x + m4.y + m4.z + m4.w;
      float p1 = m4.x * m4.x + m4.y * m4.y + m4.z * m4.z + m4.w * m4.w;
      float p2 = m4.x * v4.x + m4.y * v4.y + m4.z * v4.z + m4.w * v4.w;
      float p3 = v4.x + v4.y + v4.z + v4.w;
      float p4 = v4.x * v4.x + v4.y * v4.y + v4.z * v4.z + v4.w * v4.w;
      float p5 = m4.x * vb4.x + m4.y * vb4.y + m4.z * vb4.z + m4.w * vb4.w;
      float p6 = v4.x * vb4.x + v4.y * vb4.y + v4.z * vb4.z + v4.w * vb4.w;
      #pragma unroll
      for (int off = 32; off; off >>= 1) {
        p0 += __shfl_xor(p0, off); p1 += __shfl_xor(p1, off);
        p2 += __shfl_xor(p2, off); p3 += __shfl_xor(p3, off);
        p4 += __shfl_xor(p4, off); p5 += __shfl_xor(p5, off);
        p6 += __shfl_xor(p6, off);
      }
      const float S_Mx = p0, S_Mx2 = p1, S_Mxv = p2, S_v = p3, S_v2 = p4,
                  S_Mxb = p5, S_vvb = p6;

      // ---- scalar chain (all 64 lanes redundantly) ----
      float s_hp = projscale(S_h2);
      float xn = sqrtf(s_hp * s_hp * S_h2 + 2.f * s_hp * EPSV * S_h + 256.f * EPSV * EPSV);
      float mxn = sqrtf(S_Mx2 + 2.f * EPSV * S_Mx + 256.f * EPSV * EPSV);
      float at = 0.34657359f * flog2((1.f + xn) * frcp(1.f - xn));
      float arg = mxn * frcp(xn) * at;
      float e2 = fexp2(arg * 2.8853902f);
      float th = 1.f - 2.f * frcp(e2 + 1.f);
      float g = th * frcp(mxn);                   // Wh_pre = g*Mx
      float beta = g * projscale(g * g * S_Mx2);  // Wh = beta*Mx (projected)

      // mob_add(Wh, v)
      float nuv = 2.f * beta * S_Mxv;
      float nu  = beta * beta * S_Mx2;
      float nv  = S_v2;
      float rden = frcp(1.f + nuv + nv * nu);
      float cA = (1.f + nuv + nv) * rden;
      float cB = (1.f - nu) * rden;
      float cAb = cA * beta;                      // r1 = cAb*Mx + cB*v
      float S_r1  = cAb * S_Mx + cB * S_v;
      float S_r12 = cAb * cAb * S_Mx2 + 2.f * cAb * cB * S_Mxv + cB * cB * S_v2;
      float S_r1b = cAb * S_Mxb + cB * S_vvb;
      float s1p = projscale(S_r12);
      float S_U = s1p * S_r1, S_U2 = s1p * s1p * S_r12, S_Ub = s1p * S_r1b;

      // mob_add(U, b)
      float nuv2 = 2.f * S_Ub;
      float rden2 = frcp(1.f + nuv2 + S_vb2 * S_U2);
      float dA = (1.f + nuv2 + S_vb2) * rden2;
      float dB = (1.f - S_U2) * rden2;            // h_pre = dA*U + dB*vb
      float S_hn  = dA * S_U + dB * S_vb;
      float S_hn2 = dA * dA * S_U2 + 2.f * dA * dB * S_Ub + dB * dB * S_vb2;
      float s2p = projscale(S_hn2);

      float km = s2p * dA * s1p * cAb;
      float kv = s2p * dA * s1p * cB;
      float kb = s2p * dB;

      float4 hn;
      hn.x = km * m4.x + kv * v4.x + kb * vb4.x;
      hn.y = km * m4.y + kv * v4.y + kb * vb4.y;
      hn.z = km * m4.z + kv * v4.z + kb * vb4.z;
      hn.w = km * m4.w + kv * v4.w + kb * vb4.w;
      outw[rb4 + t * 64 + lane] = hn;

      S_h  = s2p * S_hn;
      S_h2 = s2p * s2p * S_hn2;
      float snext = projscale(S_h2);
      float4 hq;
      hq.x = snext * hn.x; hq.y = snext * hn.y; hq.z = snext * hn.z; hq.w = snext * hn.w;
      reinterpret_cast<float4*>(h_lds)[lane] = hq;
    }
    __syncthreads();                             // h ready for next step
  }
}

extern "C" void kernel_launch(void* const* d_in, const int* in_sizes, int n_in,
                              void* d_out, int out_size, void* d_ws, size_t ws_size,
                              hipStream_t stream) {
  const float* x = (const float*)d_in[0];   // [B,S,I]
  const float* w = (const float*)d_in[1];   // [H,H]
  const float* u = (const float*)d_in[2];   // [I,H]
  const float* b = (const float*)d_in[3];   // [H]
  float* out = (float*)d_out;               // [B,S,H]

  const int nrows = in_sizes[0] / 256;      // B*S
  const int S = 512;
  const int B = nrows / S;

  ux_kernel<<<nrows / 32, 256, 0, stream>>>(x, u, out);
  rnn_kernel<<<B, 512, 0, stream>>>(w, b, out, S);
}

// Round 3
// 899.926 us; speedup vs baseline: 1.7188x; 1.0682x over previous
//
#include <hip/hip_runtime.h>

#define EPSV 1e-15f
#define PEPS 1e-5f

__device__ __forceinline__ float frcp(float x) { return __builtin_amdgcn_rcpf(x); }
__device__ __forceinline__ float fexp2(float x) { return __builtin_amdgcn_exp2f(x); }
__device__ __forceinline__ float flog2(float x) { return __builtin_amdgcn_logf(x); }
// projection scale: exactly 1.0 when norm² <= 1-PEPS (matches reference), else (1-PEPS)/n2
__device__ __forceinline__ float projscale(float n2) {
  return n2 > (1.f - PEPS) ? (1.f - PEPS) * frcp(n2) : 1.f;
}

// ---------------- Kernel A: Ux[b,t,:] = mob_mat_mul(u, x[b,t,:]) -> out ----------------
// (unchanged from round 2)
__global__ __launch_bounds__(256) void ux_kernel(
    const float* __restrict__ x, const float* __restrict__ u,
    float* __restrict__ out)
{
  __shared__ __align__(16) float xsT[256][36];

  const int tid = threadIdx.x;
  const int lane = tid & 63, wv = tid >> 6;
  const long long base = (long long)blockIdx.x * 32;

  #pragma unroll
  for (int k4 = 0; k4 < 8; ++k4) {
    float t0 = x[(base + k4 * 4 + 0) * 256 + tid];
    float t1 = x[(base + k4 * 4 + 1) * 256 + tid];
    float t2 = x[(base + k4 * 4 + 2) * 256 + tid];
    float t3 = x[(base + k4 * 4 + 3) * 256 + tid];
    float4 v; v.x = t0; v.y = t1; v.z = t2; v.w = t3;
    *reinterpret_cast<float4*>(&xsT[tid][k4 * 4]) = v;
  }
  __syncthreads();

  float s1[8], s2[8];
  #pragma unroll
  for (int r = 0; r < 8; ++r) { s1[r] = 0.f; s2[r] = 0.f; }
  #pragma unroll
  for (int c = 0; c < 4; ++c) {
    const int i = lane + 64 * c;
    float4 xa = *reinterpret_cast<const float4*>(&xsT[i][8 * wv]);
    float4 xb = *reinterpret_cast<const float4*>(&xsT[i][8 * wv + 4]);
    s1[0] += xa.x; s2[0] += xa.x * xa.x;
    s1[1] += xa.y; s2[1] += xa.y * xa.y;
    s1[2] += xa.z; s2[2] += xa.z * xa.z;
    s1[3] += xa.w; s2[3] += xa.w * xa.w;
    s1[4] += xb.x; s2[4] += xb.x * xb.x;
    s1[5] += xb.y; s2[5] += xb.y * xb.y;
    s1[6] += xb.z; s2[6] += xb.z * xb.z;
    s1[7] += xb.w; s2[7] += xb.w * xb.w;
  }
  #pragma unroll
  for (int off = 32; off; off >>= 1) {
    #pragma unroll
    for (int r = 0; r < 8; ++r) {
      s1[r] += __shfl_xor(s1[r], off);
      s2[r] += __shfl_xor(s2[r], off);
    }
  }
  float rs[8], xnr[8];
  #pragma unroll
  for (int r = 0; r < 8; ++r) {
    float sc = projscale(s2[r]);
    rs[r] = sc;
    xnr[r] = sqrtf(sc * sc * s2[r] + 2.f * sc * EPSV * s1[r] + 256.f * EPSV * EPSV);
  }

  float4 acc[8];
  #pragma unroll
  for (int r = 0; r < 8; ++r) { acc[r].x = 0.f; acc[r].y = 0.f; acc[r].z = 0.f; acc[r].w = 0.f; }
  #pragma unroll 2
  for (int i = 0; i < 256; ++i) {
    float4 uv = *reinterpret_cast<const float4*>(&u[i * 256 + 4 * lane]);
    float4 xa = *reinterpret_cast<const float4*>(&xsT[i][8 * wv]);
    float4 xb = *reinterpret_cast<const float4*>(&xsT[i][8 * wv + 4]);
    acc[0].x += uv.x * xa.x; acc[0].y += uv.y * xa.x; acc[0].z += uv.z * xa.x; acc[0].w += uv.w * xa.x;
    acc[1].x += uv.x * xa.y; acc[1].y += uv.y * xa.y; acc[1].z += uv.z * xa.y; acc[1].w += uv.w * xa.y;
    acc[2].x += uv.x * xa.z; acc[2].y += uv.y * xa.z; acc[2].z += uv.z * xa.z; acc[2].w += uv.w * xa.z;
    acc[3].x += uv.x * xa.w; acc[3].y += uv.y * xa.w; acc[3].z += uv.z * xa.w; acc[3].w += uv.w * xa.w;
    acc[4].x += uv.x * xb.x; acc[4].y += uv.y * xb.x; acc[4].z += uv.z * xb.x; acc[4].w += uv.w * xb.x;
    acc[5].x += uv.x * xb.y; acc[5].y += uv.y * xb.y; acc[5].z += uv.z * xb.y; acc[5].w += uv.w * xb.y;
    acc[6].x += uv.x * xb.z; acc[6].y += uv.y * xb.z; acc[6].z += uv.z * xb.z; acc[6].w += uv.w * xb.z;
    acc[7].x += uv.x * xb.w; acc[7].y += uv.y * xb.w; acc[7].z += uv.z * xb.w; acc[7].w += uv.w * xb.w;
  }

  float t1s[8], t2s[8];
  #pragma unroll
  for (int r = 0; r < 8; ++r) {
    t1s[r] = acc[r].x + acc[r].y + acc[r].z + acc[r].w;
    t2s[r] = acc[r].x * acc[r].x + acc[r].y * acc[r].y + acc[r].z * acc[r].z + acc[r].w * acc[r].w;
  }
  #pragma unroll
  for (int off = 32; off; off >>= 1) {
    #pragma unroll
    for (int r = 0; r < 8; ++r) {
      t1s[r] += __shfl_xor(t1s[r], off);
      t2s[r] += __shfl_xor(t2s[r], off);
    }
  }
  #pragma unroll
  for (int r = 0; r < 8; ++r) {
    float Sm  = rs[r] * t1s[r];
    float Sm2 = rs[r] * rs[r] * t2s[r];
    float mxn = sqrtf(Sm2 + 2.f * EPSV * Sm + 256.f * EPSV * EPSV);
    float xn = xnr[r];
    float at = 0.34657359f * flog2((1.f + xn) * frcp(1.f - xn));
    float arg = mxn * frcp(xn) * at;
    float e2 = fexp2(arg * 2.8853902f);
    float th = 1.f - 2.f * frcp(e2 + 1.f);
    float g = th * frcp(mxn);
    float fs = g * projscale(g * g * Sm2) * rs[r];
    float4 o;
    o.x = fs * acc[r].x; o.y = fs * acc[r].y; o.z = fs * acc[r].z; o.w = fs * acc[r].w;
    reinterpret_cast<float4*>(out)[(base + 8 * wv + r) * 64 + lane] = o;
  }
}

// ---------------- Kernel B: sequential recurrence with matvec/chain overlap ----------------
// 576 threads = 9 waves. Waves 1-8: hold W slice (32 K-rows x 4 cols) in 128 VGPRs, compute
// P=W@Mx[t] and Q=W@ux[t] each step (independent of the chain). Wave 0: dots + scalar chain +
// output write + combine Mx[t+1] = snext*(km*P + kv*(Q+EPS*W1) + kb*Wvb).
__global__ __launch_bounds__(576, 1) void rnn_kernel(
    const float* __restrict__ w, const float* __restrict__ bvec,
    float* __restrict__ out, int S)
{
  __shared__ __align__(16) float mx_lds[256];      // combined Mx[t]
  __shared__ __align__(16) float v_lds[2][256];    // raw ux (double buffer)
  __shared__ __align__(16) float pP[8][256];
  __shared__ __align__(16) float pQ[8][256];

  const int tid = threadIdx.x;
  const int lane = tid & 63;
  const int wv = tid >> 6;                         // 0..8

  const long long rb4 = (long long)blockIdx.x * S * 64;   // float4 units
  const float4* outv = reinterpret_cast<const float4*>(out);
  float4* outw = reinterpret_cast<float4*>(out);

  if (wv >= 1) {
    // ---- matvec wave: rows (wv-1)*32..+31, cols 4*lane..+3 ----
    const int ks = (wv - 1) * 32;
    float4 wreg[32];
    #pragma unroll
    for (int ii = 0; ii < 32; ++ii)
      wreg[ii] = *reinterpret_cast<const float4*>(&w[(ks + ii) * 256 + 4 * lane]);

    __syncthreads();  // (1) vb staged in v_lds[0], mx_lds zeroed
    {
      float4 p = {0.f,0.f,0.f,0.f}, q = {0.f,0.f,0.f,0.f};
      const float4* vbp = reinterpret_cast<const float4*>(&v_lds[0][ks]);
      #pragma unroll
      for (int i4 = 0; i4 < 8; ++i4) {
        float4 b4 = vbp[i4];
        float4 w0 = wreg[i4*4+0], w1 = wreg[i4*4+1], w2 = wreg[i4*4+2], w3 = wreg[i4*4+3];
        p.x += w0.x*b4.x; p.y += w0.y*b4.x; p.z += w0.z*b4.x; p.w += w0.w*b4.x;
        p.x += w1.x*b4.y; p.y += w1.y*b4.y; p.z += w1.z*b4.y; p.w += w1.w*b4.y;
        p.x += w2.x*b4.z; p.y += w2.y*b4.z; p.z += w2.z*b4.z; p.w += w2.w*b4.z;
        p.x += w3.x*b4.w; p.y += w3.y*b4.w; p.z += w3.z*b4.w; p.w += w3.w*b4.w;
        q.x += (w0.x + w1.x) + (w2.x + w3.x);
        q.y += (w0.y + w1.y) + (w2.y + w3.y);
        q.z += (w0.z + w1.z) + (w2.z + w3.z);
        q.w += (w0.w + w1.w) + (w2.w + w3.w);
      }
      *reinterpret_cast<float4*>(&pP[wv-1][4*lane]) = p;
      *reinterpret_cast<float4*>(&pQ[wv-1][4*lane]) = q;
    }
    __syncthreads();  // (2) init partials ready
    __syncthreads();  // (3) wave0 wrote v[0] into v_lds[0]

    for (int t = 0; t < S; ++t) {
      float4 p = {0.f,0.f,0.f,0.f}, q = {0.f,0.f,0.f,0.f};
      const float4* hp = reinterpret_cast<const float4*>(&mx_lds[ks]);
      const float4* vp = reinterpret_cast<const float4*>(&v_lds[t & 1][ks]);
      #pragma unroll
      for (int i4 = 0; i4 < 8; ++i4) {
        float4 h4 = hp[i4];
        float4 v4 = vp[i4];
        float4 w0 = wreg[i4*4+0], w1 = wreg[i4*4+1], w2 = wreg[i4*4+2], w3 = wreg[i4*4+3];
        p.x += w0.x*h4.x; p.y += w0.y*h4.x; p.z += w0.z*h4.x; p.w += w0.w*h4.x;
        p.x += w1.x*h4.y; p.y += w1.y*h4.y; p.z += w1.z*h4.y; p.w += w1.w*h4.y;
        p.x += w2.x*h4.z; p.y += w2.y*h4.z; p.z += w2.z*h4.z; p.w += w2.w*h4.z;
        p.x += w3.x*h4.w; p.y += w3.y*h4.w; p.z += w3.z*h4.w; p.w += w3.w*h4.w;
        q.x += w0.x*v4.x; q.y += w0.y*v4.x; q.z += w0.z*v4.x; q.w += w0.w*v4.x;
        q.x += w1.x*v4.y; q.y += w1.y*v4.y; q.z += w1.z*v4.y; q.w += w1.w*v4.y;
        q.x += w2.x*v4.z; q.y += w2.y*v4.z; q.z += w2.z*v4.z; q.w += w2.w*v4.z;
        q.x += w3.x*v4.w; q.y += w3.y*v4.w; q.z += w3.z*v4.w; q.w += w3.w*v4.w;
      }
      *reinterpret_cast<float4*>(&pP[wv-1][4*lane]) = p;
      *reinterpret_cast<float4*>(&pQ[wv-1][4*lane]) = q;
      __syncthreads();   // B: partials ready
      __syncthreads();   // A: mx[t+1] + staged v ready
    }
  } else {
    // ---- wave 0: reductions, scalar chain, combine ----
    float4 vb4 = *reinterpret_cast<const float4*>(&bvec[4 * lane]);
    vb4.x += EPSV; vb4.y += EPSV; vb4.z += EPSV; vb4.w += EPSV;

    float S_vb  = vb4.x + vb4.y + vb4.z + vb4.w;
    float S_vb2 = vb4.x * vb4.x + vb4.y * vb4.y + vb4.z * vb4.z + vb4.w * vb4.w;
    #pragma unroll
    for (int off = 32; off; off >>= 1) {
      S_vb  += __shfl_xor(S_vb, off);
      S_vb2 += __shfl_xor(S_vb2, off);
    }

    reinterpret_cast<float4*>(mx_lds)[lane] = float4{0.f,0.f,0.f,0.f};
    reinterpret_cast<float4*>(v_lds[0])[lane] = vb4;     // stage vb for init matvec
    __syncthreads();  // (1)

    float4 vA = outv[rb4 + lane];        // v[0]
    float4 vB = outv[rb4 + 64 + lane];   // v[1]
    __syncthreads();  // (2) init partials ready

    float4 Wvb4 = {0.f,0.f,0.f,0.f}, W1_4 = {0.f,0.f,0.f,0.f};
    #pragma unroll
    for (int k = 0; k < 8; ++k) {
      float4 pp = *reinterpret_cast<const float4*>(&pP[k][4*lane]);
      float4 qq = *reinterpret_cast<const float4*>(&pQ[k][4*lane]);
      Wvb4.x += pp.x; Wvb4.y += pp.y; Wvb4.z += pp.z; Wvb4.w += pp.w;
      W1_4.x += qq.x; W1_4.y += qq.y; W1_4.z += qq.z; W1_4.w += qq.w;
    }
    reinterpret_cast<float4*>(v_lds[0])[lane] = vA;      // real v[0]
    __syncthreads();  // (3)

    float4 m4 = {0.f,0.f,0.f,0.f};                       // Mx[0] = 0 (h0 = 0)
    float S_h = 0.f, S_h2 = 0.f;

    for (int t = 0; t < S; ++t) {
      float4 v4 = vA;
      v4.x += EPSV; v4.y += EPSV; v4.z += EPSV; v4.w += EPSV;

      // 7 dots over 256 cols (4/lane, butterfly)
      float p0 = m4.x + m4.y + m4.z + m4.w;
      float p1 = m4.x * m4.x + m4.y * m4.y + m4.z * m4.z + m4.w * m4.w;
      float p2 = m4.x * v4.x + m4.y * v4.y + m4.z * v4.z + m4.w * v4.w;
      float p3 = v4.x + v4.y + v4.z + v4.w;
      float p4 = v4.x * v4.x + v4.y * v4.y + v4.z * v4.z + v4.w * v4.w;
      float p5 = m4.x * vb4.x + m4.y * vb4.y + m4.z * vb4.z + m4.w * vb4.w;
      float p6 = v4.x * vb4.x + v4.y * vb4.y + v4.z * vb4.z + v4.w * vb4.w;
      #pragma unroll
      for (int off = 32; off; off >>= 1) {
        p0 += __shfl_xor(p0, off); p1 += __shfl_xor(p1, off);
        p2 += __shfl_xor(p2, off); p3 += __shfl_xor(p3, off);
        p4 += __shfl_xor(p4, off); p5 += __shfl_xor(p5, off);
        p6 += __shfl_xor(p6, off);
      }
      const float S_Mx = p0, S_Mx2 = p1, S_Mxv = p2, S_v = p3, S_v2 = p4,
                  S_Mxb = p5, S_vvb = p6;

      // scalar chain
      float s_hp = projscale(S_h2);
      float xn = sqrtf(s_hp * s_hp * S_h2 + 2.f * s_hp * EPSV * S_h + 256.f * EPSV * EPSV);
      float mxn = sqrtf(S_Mx2 + 2.f * EPSV * S_Mx + 256.f * EPSV * EPSV);
      float at = 0.34657359f * flog2((1.f + xn) * frcp(1.f - xn));
      float arg = mxn * frcp(xn) * at;
      float e2 = fexp2(arg * 2.8853902f);
      float th = 1.f - 2.f * frcp(e2 + 1.f);
      float g = th * frcp(mxn);
      float beta = g * projscale(g * g * S_Mx2);

      float nuv = 2.f * beta * S_Mxv;
      float nu  = beta * beta * S_Mx2;
      float nv  = S_v2;
      float rden = frcp(1.f + nuv + nv * nu);
      float cA = (1.f + nuv + nv) * rden;
      float cB = (1.f - nu) * rden;
      float cAb = cA * beta;
      float S_r1  = cAb * S_Mx + cB * S_v;
      float S_r12 = cAb * cAb * S_Mx2 + 2.f * cAb * cB * S_Mxv + cB * cB * S_v2;
      float S_r1b = cAb * S_Mxb + cB * S_vvb;
      float s1p = projscale(S_r12);
      float S_U = s1p * S_r1, S_U2 = s1p * s1p * S_r12, S_Ub = s1p * S_r1b;

      float nuv2 = 2.f * S_Ub;
      float rden2 = frcp(1.f + nuv2 + S_vb2 * S_U2);
      float dA = (1.f + nuv2 + S_vb2) * rden2;
      float dB = (1.f - S_U2) * rden2;
      float S_hn  = dA * S_U + dB * S_vb;
      float S_hn2 = dA * dA * S_U2 + 2.f * dA * dB * S_Ub + dB * dB * S_vb2;
      float s2p = projscale(S_hn2);

      float km = s2p * dA * s1p * cAb;
      float kv = s2p * dA * s1p * cB;
      float kb = s2p * dB;

      float4 hn;
      hn.x = km * m4.x + kv * v4.x + kb * vb4.x;
      hn.y = km * m4.y + kv * v4.y + kb * vb4.y;
      hn.z = km * m4.z + kv * v4.z + kb * vb4.z;
      hn.w = km * m4.w + kv * v4.w + kb * vb4.w;
      outw[rb4 + t * 64 + lane] = hn;

      S_h  = s2p * S_hn;
      S_h2 = s2p * s2p * S_hn2;
      float snext = projscale(S_h2);

      // stage v[t+1] into LDS; issue prefetch of v[t+2]
      if (t + 1 < S) reinterpret_cast<float4*>(v_lds[(t + 1) & 1])[lane] = vB;
      float4 vC = vB;
      if (t + 2 < S) vC = outv[rb4 + (t + 2) * 64 + lane];

      __syncthreads();   // B: P/Q partials ready

      // combine: Mx[t+1] = snext*(km*P + kv*(Q + EPS*W1) + kb*Wvb)
      float4 Pc = {0.f,0.f,0.f,0.f}, Qc = {0.f,0.f,0.f,0.f};
      #pragma unroll
      for (int k = 0; k < 8; ++k) {
        float4 pp = *reinterpret_cast<const float4*>(&pP[k][4*lane]);
        float4 qq = *reinterpret_cast<const float4*>(&pQ[k][4*lane]);
        Pc.x += pp.x; Pc.y += pp.y; Pc.z += pp.z; Pc.w += pp.w;
        Qc.x += qq.x; Qc.y += qq.y; Qc.z += qq.z; Qc.w += qq.w;
      }
      m4.x = snext * (km * Pc.x + kv * (Qc.x + EPSV * W1_4.x) + kb * Wvb4.x);
      m4.y = snext * (km * Pc.y + kv * (Qc.y + EPSV * W1_4.y) + kb * Wvb4.y);
      m4.z = snext * (km * Pc.z + kv * (Qc.z + EPSV * W1_4.z) + kb * Wvb4.z);
      m4.w = snext * (km * Pc.w + kv * (Qc.w + EPSV * W1_4.w) + kb * Wvb4.w);
      reinterpret_cast<float4*>(mx_lds)[lane] = m4;

      vA = vB; vB = vC;
      __syncthreads();   // A
    }
  }
}

extern "C" void kernel_launch(void* const* d_in, const int* in_sizes, int n_in,
                              void* d_out, int out_size, void* d_ws, size_t ws_size,
                              hipStream_t stream) {
  const float* x = (const float*)d_in[0];   // [B,S,I]
  const float* w = (const float*)d_in[1];   // [H,H]
  const float* u = (const float*)d_in[2];   // [I,H]
  const float* b = (const float*)d_in[3];   // [H]
  float* out = (float*)d_out;               // [B,S,H]

  const int nrows = in_sizes[0] / 256;      // B*S
  const int S = 512;
  const int B = nrows / S;

  ux_kernel<<<nrows / 32, 256, 0, stream>>>(x, u, out);
  rnn_kernel<<<B, 576, 0, stream>>>(w, b, out, S);
}